// Round 1
// baseline (2622.618 us; speedup 1.0000x reference)
//
#include <hip/hip_runtime.h>
#include <hip/hip_bf16.h>
#include <math.h>

// Problem constants (reference: B=2, S=2048, D=1024, H=16, DK=64)
#define BB 2
#define SS 2048
#define DD 1024
#define HH 16
#define DK 64
#define NT (BB * SS)   // 4096 tokens

// ---------------------------------------------------------------------------
// GEMM: C[M][N] = A[M][K] @ W[N][K]^T + bias[N]   (torch Linear semantics)
// fp32, BM=BN=64, BK=16, 256 threads, 4x4 micro-tile per thread.
// ---------------------------------------------------------------------------
__global__ __launch_bounds__(256)
void gemm_bias_f32(const float* __restrict__ A,
                   const float* __restrict__ W,
                   const float* __restrict__ bias,
                   float* __restrict__ C,
                   int M, int N, int K) {
    __shared__ float As[16][64 + 1];
    __shared__ float Ws[16][64 + 1];

    const int tid = threadIdx.x;
    const int bm = blockIdx.y * 64;
    const int bn = blockIdx.x * 64;
    const int ty = tid >> 4;        // 0..15 -> C-tile row group
    const int tx = tid & 15;        // 0..15 -> C-tile col group

    float acc[4][4] = {};

    const int lr = tid >> 2;            // 0..63 load row
    const int lc4 = (tid & 3) * 4;      // 0,4,8,12 load col (float4)

    for (int kt = 0; kt < K; kt += 16) {
        const float4 av = *reinterpret_cast<const float4*>(&A[(size_t)(bm + lr) * K + kt + lc4]);
        As[lc4 + 0][lr] = av.x; As[lc4 + 1][lr] = av.y;
        As[lc4 + 2][lr] = av.z; As[lc4 + 3][lr] = av.w;
        const float4 wv = *reinterpret_cast<const float4*>(&W[(size_t)(bn + lr) * K + kt + lc4]);
        Ws[lc4 + 0][lr] = wv.x; Ws[lc4 + 1][lr] = wv.y;
        Ws[lc4 + 2][lr] = wv.z; Ws[lc4 + 3][lr] = wv.w;
        __syncthreads();

        #pragma unroll
        for (int kk = 0; kk < 16; ++kk) {
            float a[4], w[4];
            #pragma unroll
            for (int i = 0; i < 4; ++i) a[i] = As[kk][ty * 4 + i];
            #pragma unroll
            for (int j = 0; j < 4; ++j) w[j] = Ws[kk][tx * 4 + j];
            #pragma unroll
            for (int i = 0; i < 4; ++i)
                #pragma unroll
                for (int j = 0; j < 4; ++j)
                    acc[i][j] += a[i] * w[j];
        }
        __syncthreads();
    }

    #pragma unroll
    for (int i = 0; i < 4; ++i) {
        const int row = bm + ty * 4 + i;
        #pragma unroll
        for (int j = 0; j < 4; ++j) {
            const int col = bn + tx * 4 + j;
            C[(size_t)row * N + col] = acc[i][j] + bias[col];
        }
    }
}

// ---------------------------------------------------------------------------
// Causal flash attention over token-major q/k/v buffers ([4096][1024], fp32;
// head h occupies columns h*64..h*64+63). One block = (b, h, 64-row q tile).
// Online softmax; row state shared across the 4 threads of each row group
// via __shfl_xor(width=4). Mask input is tril -> causal handled structurally.
// ---------------------------------------------------------------------------
__global__ __launch_bounds__(256)
void attn_causal_f32(const float* __restrict__ Q,
                     const float* __restrict__ Kb,
                     const float* __restrict__ Vb,
                     float* __restrict__ X) {
    const int qt = blockIdx.x;      // q tile index (0..31)
    const int h  = blockIdx.y;      // head
    const int b  = blockIdx.z;      // batch
    const int tid = threadIdx.x;
    const int r  = tid >> 2;        // row within tile (0..63)
    const int cg = tid & 3;         // column group (0..3)
    const int cb = cg * 16;         // column base (0,16,32,48)

    __shared__ float qs[64][65];
    __shared__ float kp[64][65];    // K tile, reused for P after scores
    __shared__ float vs[64][65];

    const float scale = 0.125f;     // 1/sqrt(64)
    const int tok0 = b * SS + qt * 64;
    const int col0 = h * DK;

    // load Q tile (64x64)
    {
        const int lr0 = tid >> 4;          // 0..15
        const int c4 = (tid & 15) * 4;     // 0..60 step 4
        for (int rr = lr0; rr < 64; rr += 16) {
            const float4 v4 = *reinterpret_cast<const float4*>(&Q[(size_t)(tok0 + rr) * DD + col0 + c4]);
            qs[rr][c4 + 0] = v4.x; qs[rr][c4 + 1] = v4.y;
            qs[rr][c4 + 2] = v4.z; qs[rr][c4 + 3] = v4.w;
        }
    }
    __syncthreads();

    float m = -INFINITY, l = 0.f;
    float o[16];
    #pragma unroll
    for (int j = 0; j < 16; ++j) o[j] = 0.f;

    for (int kt = 0; kt <= qt; ++kt) {
        const int ktok0 = b * SS + kt * 64;
        // load K and V tiles
        {
            const int lr0 = tid >> 4;
            const int c4 = (tid & 15) * 4;
            for (int rr = lr0; rr < 64; rr += 16) {
                const float4 kv = *reinterpret_cast<const float4*>(&Kb[(size_t)(ktok0 + rr) * DD + col0 + c4]);
                kp[rr][c4 + 0] = kv.x; kp[rr][c4 + 1] = kv.y;
                kp[rr][c4 + 2] = kv.z; kp[rr][c4 + 3] = kv.w;
                const float4 vv = *reinterpret_cast<const float4*>(&Vb[(size_t)(ktok0 + rr) * DD + col0 + c4]);
                vs[rr][c4 + 0] = vv.x; vs[rr][c4 + 1] = vv.y;
                vs[rr][c4 + 2] = vv.z; vs[rr][c4 + 3] = vv.w;
            }
        }
        __syncthreads();

        // scores for row r, cols cb..cb+15
        float s[16];
        #pragma unroll
        for (int j = 0; j < 16; ++j) s[j] = 0.f;
        for (int d = 0; d < 64; ++d) {
            const float qv = qs[r][d];
            #pragma unroll
            for (int j = 0; j < 16; ++j)
                s[j] += qv * kp[cb + j][d];
        }

        float tmax = -INFINITY;
        #pragma unroll
        for (int j = 0; j < 16; ++j) {
            s[j] *= scale;
            if (kt == qt && (cb + j) > r) s[j] = -1e30f;  // causal mask on diagonal tile
            tmax = fmaxf(tmax, s[j]);
        }
        tmax = fmaxf(tmax, __shfl_xor(tmax, 1, 4));
        tmax = fmaxf(tmax, __shfl_xor(tmax, 2, 4));

        const float mnew = fmaxf(m, tmax);
        const float corr = expf(m - mnew);
        float psum = 0.f;
        #pragma unroll
        for (int j = 0; j < 16; ++j) {
            s[j] = expf(s[j] - mnew);
            psum += s[j];
        }
        psum += __shfl_xor(psum, 1, 4);
        psum += __shfl_xor(psum, 2, 4);
        l = l * corr + psum;
        m = mnew;
        #pragma unroll
        for (int j = 0; j < 16; ++j) o[j] *= corr;

        __syncthreads();            // everyone done reading kp as K
        #pragma unroll
        for (int j = 0; j < 16; ++j) kp[r][cb + j] = s[j];
        __syncthreads();            // P visible

        // PV: o[j] (dk = cb+j) += sum_c p[r][c] * v[c][cb+j]
        for (int c = 0; c < 64; ++c) {
            const float p = kp[r][c];
            #pragma unroll
            for (int j = 0; j < 16; ++j)
                o[j] += p * vs[c][cb + j];
        }
        __syncthreads();            // before next tile overwrites kp/vs
    }

    const float inv = 1.f / l;
    #pragma unroll
    for (int j = 0; j < 16; ++j)
        X[(size_t)(tok0 + r) * DD + col0 + cb + j] = o[j] * inv;
}

// ---------------------------------------------------------------------------
extern "C" void kernel_launch(void* const* d_in, const int* in_sizes, int n_in,
                              void* d_out, int out_size, void* d_ws, size_t ws_size,
                              hipStream_t stream) {
    const float* query = (const float*)d_in[0];
    const float* key   = (const float*)d_in[1];
    const float* value = (const float*)d_in[2];
    // d_in[3] = mask (int32 tril) — causal structure handled in-kernel
    const float* Wq = (const float*)d_in[4];
    const float* bq = (const float*)d_in[5];
    const float* Wk = (const float*)d_in[6];
    const float* bk = (const float*)d_in[7];
    const float* Wv = (const float*)d_in[8];
    const float* bv = (const float*)d_in[9];
    const float* Wo = (const float*)d_in[10];
    const float* bo = (const float*)d_in[11];
    float* out = (float*)d_out;

    float* ws = (float*)d_ws;
    const size_t buf = (size_t)NT * DD;   // 4M floats = 16.78 MB
    float* qb = ws;
    float* kb = ws + buf;
    float* vb = ws + 2 * buf;
    float* xb = ws + 3 * buf;

    const dim3 gblk(256);
    const dim3 ggrid(DD / 64, NT / 64);   // (16, 64)

    gemm_bias_f32<<<ggrid, gblk, 0, stream>>>(query, Wq, bq, qb, NT, DD, DD);
    gemm_bias_f32<<<ggrid, gblk, 0, stream>>>(key,   Wk, bk, kb, NT, DD, DD);
    gemm_bias_f32<<<ggrid, gblk, 0, stream>>>(value, Wv, bv, vb, NT, DD, DD);

    attn_causal_f32<<<dim3(SS / 64, HH, BB), gblk, 0, stream>>>(qb, kb, vb, xb);

    gemm_bias_f32<<<ggrid, gblk, 0, stream>>>(xb, Wo, bo, out, NT, DD, DD);
}

// Round 2
// 369.376 us; speedup vs baseline: 7.1001x; 7.1001x over previous
//
#include <hip/hip_runtime.h>
#include <hip/hip_bf16.h>
#include <math.h>

#define BB 2
#define SS 2048
#define DD 1024
#define HH 16
#define DKK 64
#define NT (BB * SS)   // 4096 tokens

typedef __attribute__((ext_vector_type(8))) short short8;   // 8 bf16 = 4 VGPRs
typedef __attribute__((ext_vector_type(4))) float f32x4;

// XOR swizzle for 128B rows (8 x 16B chunks): spreads bank sets
#define SWZ(r) ((((r) >> 3) ^ (r)) & 7)

__device__ __forceinline__ unsigned short f2b(float f) {
    union { float f; unsigned u; } c; c.f = f;
    unsigned r = c.u + 0x7FFFu + ((c.u >> 16) & 1u);   // RNE
    return (unsigned short)(r >> 16);
}

__device__ __forceinline__ f32x4 zero4() {
    f32x4 z; z[0] = 0.f; z[1] = 0.f; z[2] = 0.f; z[3] = 0.f; return z;
}

// ---------------------------------------------------------------------------
// fp32 -> bf16 cast (vectorized, grid-stride)
// ---------------------------------------------------------------------------
__global__ __launch_bounds__(256)
void cast_f32_bf16(const float* __restrict__ in, unsigned short* __restrict__ out, int n4) {
    int i = blockIdx.x * 256 + threadIdx.x;
    const int stride = gridDim.x * 256;
    for (; i < n4; i += stride) {
        const float4 v = reinterpret_cast<const float4*>(in)[i];
        ushort4 o;
        o.x = f2b(v.x); o.y = f2b(v.y); o.z = f2b(v.z); o.w = f2b(v.w);
        reinterpret_cast<ushort4*>(out)[i] = o;
    }
}

// ---------------------------------------------------------------------------
// bf16 MFMA GEMM: C[M][N] = A[M][K] @ W[N][K]^T + bias
// 128x128 tile, BK=64, 4 waves, each wave 64x64 (4x4 fragments of 16x16x32).
// LDS rows are 128B, XOR-swizzled in 16B chunks.
// ---------------------------------------------------------------------------
template <typename OutT>
__global__ __launch_bounds__(256)
void gemm_bf16_mfma(const unsigned short* __restrict__ A,
                    const unsigned short* __restrict__ W,
                    const float* __restrict__ bias,
                    OutT* __restrict__ C,
                    int M, int N, int K) {
    __shared__ __align__(16) unsigned char sA[128 * 128];  // 128 rows x 64 bf16
    __shared__ __align__(16) unsigned char sB[128 * 128];

    const int tid = threadIdx.x;
    const int l = tid & 63;
    const int w = tid >> 6;
    const int wr = w >> 1, wc = w & 1;
    const int g = l >> 4, li = l & 15;
    const int bm = blockIdx.y * 128;
    const int bn = blockIdx.x * 128;

    f32x4 acc[4][4];
    #pragma unroll
    for (int i = 0; i < 4; ++i)
        #pragma unroll
        for (int j = 0; j < 4; ++j) acc[i][j] = zero4();

    for (int kt = 0; kt < K; kt += 64) {
        // stage A-tile and B-tile (coalesced: lane covers contiguous 16B chunk)
        #pragma unroll
        for (int c = 0; c < 4; ++c) {
            const int ch = c * 256 + tid;
            const int row = ch >> 3, cj = ch & 7;
            const short8 va = *reinterpret_cast<const short8*>(&A[(size_t)(bm + row) * K + kt + cj * 8]);
            *reinterpret_cast<short8*>(&sA[row * 128 + ((cj ^ SWZ(row)) << 4)]) = va;
            const short8 vb = *reinterpret_cast<const short8*>(&W[(size_t)(bn + row) * K + kt + cj * 8]);
            *reinterpret_cast<short8*>(&sB[row * 128 + ((cj ^ SWZ(row)) << 4)]) = vb;
        }
        __syncthreads();

        #pragma unroll
        for (int kb = 0; kb < 2; ++kb) {
            short8 af[4], bfr[4];
            const int ch = g + kb * 4;
            #pragma unroll
            for (int mi = 0; mi < 4; ++mi) {
                const int row = wr * 64 + mi * 16 + li;
                af[mi] = *reinterpret_cast<const short8*>(&sA[row * 128 + ((ch ^ SWZ(row)) << 4)]);
            }
            #pragma unroll
            for (int ni = 0; ni < 4; ++ni) {
                const int row = wc * 64 + ni * 16 + li;
                bfr[ni] = *reinterpret_cast<const short8*>(&sB[row * 128 + ((ch ^ SWZ(row)) << 4)]);
            }
            #pragma unroll
            for (int mi = 0; mi < 4; ++mi)
                #pragma unroll
                for (int ni = 0; ni < 4; ++ni)
                    acc[mi][ni] = __builtin_amdgcn_mfma_f32_16x16x32_bf16(af[mi], bfr[ni], acc[mi][ni], 0, 0, 0);
        }
        __syncthreads();
    }

    // epilogue: bias + store (C/D layout: col=l&15, row=(l>>4)*4+reg)
    #pragma unroll
    for (int ni = 0; ni < 4; ++ni) {
        const int col = bn + wc * 64 + ni * 16 + li;
        const float bv = bias[col];
        #pragma unroll
        for (int mi = 0; mi < 4; ++mi) {
            const int row0 = bm + wr * 64 + mi * 16 + g * 4;
            #pragma unroll
            for (int r = 0; r < 4; ++r) {
                const float v = acc[mi][ni][r] + bv;
                if constexpr (sizeof(OutT) == 2)
                    C[(size_t)(row0 + r) * N + col] = (OutT)f2b(v);
                else
                    C[(size_t)(row0 + r) * N + col] = (OutT)v;
            }
        }
    }
}

// ---------------------------------------------------------------------------
// bf16 MFMA causal flash attention.
// Block = (qt, h, b), 4 waves x 16 q-rows. KVBLK = 64.
// Swapped QK^T: S-frag = mfma(K_frag, Q_frag) -> lane holds S[kv][q=l&15];
// softmax row-reduce = in-lane over 16 + shfl_xor(16,32).
// P round-trips through per-wave swizzled LDS to become the PV A-fragment.
// V staged transposed [d][kv] so the PV B-fragment is a contiguous b128 read.
// ---------------------------------------------------------------------------
__global__ __launch_bounds__(256)
void attn_mfma(const unsigned short* __restrict__ Q,
               const unsigned short* __restrict__ Kb,
               const unsigned short* __restrict__ Vb,
               unsigned short* __restrict__ X) {
    __shared__ __align__(16) unsigned char sK[64 * 128];      // [kv][d] swizzled
    __shared__ __align__(16) unsigned char sV[64 * 128];      // [d][kv] swizzled (transposed)
    __shared__ __align__(16) unsigned char sP[4][16 * 128];   // per-wave [q][kv] swizzled

    const int qt = blockIdx.x, h = blockIdx.y, b = blockIdx.z;
    const int tid = threadIdx.x, l = tid & 63, w = tid >> 6;
    const int g = l >> 4, li = l & 15;

    const int tok0 = b * SS + qt * 64;
    const int col0 = h * DKK;
    const float scale = 0.125f;   // 1/sqrt(64)

    // Q fragments (held in registers for the whole kernel)
    short8 qf[2];
    {
        const size_t qrow = (size_t)(tok0 + w * 16 + li) * DD + col0;
        qf[0] = *reinterpret_cast<const short8*>(&Q[qrow + g * 8]);
        qf[1] = *reinterpret_cast<const short8*>(&Q[qrow + 32 + g * 8]);
    }

    f32x4 accO[4];
    #pragma unroll
    for (int i = 0; i < 4; ++i) accO[i] = zero4();
    float m = -INFINITY, lsum = 0.f;
    const int qglob = qt * 64 + w * 16 + li;   // the q-row this lane tracks

    for (int kt = 0; kt <= qt; ++kt) {
        const int ktok0 = b * SS + kt * 64;

        // stage K (row-major swizzled) + V (transposed swizzled)
        #pragma unroll
        for (int c = 0; c < 2; ++c) {
            const int ch = c * 256 + tid;
            const int row = ch >> 3, cj = ch & 7;
            const size_t gsrc = (size_t)(ktok0 + row) * DD + col0 + cj * 8;
            const short8 kv8 = *reinterpret_cast<const short8*>(&Kb[gsrc]);
            *reinterpret_cast<short8*>(&sK[row * 128 + ((cj ^ SWZ(row)) << 4)]) = kv8;
            const short8 vv8 = *reinterpret_cast<const short8*>(&Vb[gsrc]);
            #pragma unroll
            for (int j = 0; j < 8; ++j) {
                const int d = cj * 8 + j;   // transpose: Vt[d][kv=row]
                *reinterpret_cast<short*>(
                    &sV[d * 128 + (((row >> 3) ^ SWZ(d)) << 4) + (row & 7) * 2]) = vv8[j];
            }
        }
        __syncthreads();

        // S = K . Q^T  (swapped operands)
        f32x4 accS[4];
        #pragma unroll
        for (int n0 = 0; n0 < 4; ++n0) accS[n0] = zero4();
        #pragma unroll
        for (int n0 = 0; n0 < 4; ++n0) {
            #pragma unroll
            for (int kb = 0; kb < 2; ++kb) {
                const int row = n0 * 16 + li;
                const int ch = g + kb * 4;
                const short8 kf = *reinterpret_cast<const short8*>(
                    &sK[row * 128 + ((ch ^ SWZ(row)) << 4)]);
                accS[n0] = __builtin_amdgcn_mfma_f32_16x16x32_bf16(kf, qf[kb], accS[n0], 0, 0, 0);
            }
        }

        // softmax (online); lane holds 16 kv-values of row q = qglob
        float s[16];
        float tmax = -INFINITY;
        const bool diag = (kt == qt);
        #pragma unroll
        for (int n0 = 0; n0 < 4; ++n0)
            #pragma unroll
            for (int r = 0; r < 4; ++r) {
                float v = accS[n0][r] * scale;
                if (diag) {
                    const int kv = kt * 64 + n0 * 16 + g * 4 + r;
                    if (kv > qglob) v = -1e30f;
                }
                s[n0 * 4 + r] = v;
                tmax = fmaxf(tmax, v);
            }
        tmax = fmaxf(tmax, __shfl_xor(tmax, 16));
        tmax = fmaxf(tmax, __shfl_xor(tmax, 32));
        const float mnew = fmaxf(m, tmax);
        const float corr = __expf(m - mnew);
        float psum = 0.f;
        #pragma unroll
        for (int i = 0; i < 16; ++i) { s[i] = __expf(s[i] - mnew); psum += s[i]; }
        psum += __shfl_xor(psum, 16);
        psum += __shfl_xor(psum, 32);
        lsum = lsum * corr + psum;
        m = mnew;

        // write P to this wave's LDS region: row q=li, col kv
        #pragma unroll
        for (int n0 = 0; n0 < 4; ++n0)
            #pragma unroll
            for (int r = 0; r < 4; ++r) {
                const int kv = n0 * 16 + g * 4 + r;
                *reinterpret_cast<unsigned short*>(
                    &sP[w][li * 128 + (((kv >> 3) ^ SWZ(li)) << 4) + (kv & 7) * 2]) =
                    f2b(s[n0 * 4 + r]);
            }

        // rescale O by corr of q' = g*4+r (cross-lane fetch)
        float corr4[4];
        #pragma unroll
        for (int r = 0; r < 4; ++r) corr4[r] = __shfl(corr, (l & 48) | (g * 4 + r));
        #pragma unroll
        for (int n0d = 0; n0d < 4; ++n0d)
            #pragma unroll
            for (int r = 0; r < 4; ++r) accO[n0d][r] *= corr4[r];

        __syncthreads();   // P visible

        // O += P . V
        #pragma unroll
        for (int kb = 0; kb < 2; ++kb) {
            const int ch = g + kb * 4;
            const short8 pf = *reinterpret_cast<const short8*>(
                &sP[w][li * 128 + ((ch ^ SWZ(li)) << 4)]);
            #pragma unroll
            for (int n0d = 0; n0d < 4; ++n0d) {
                const int d = n0d * 16 + li;
                const short8 vf = *reinterpret_cast<const short8*>(
                    &sV[d * 128 + ((ch ^ SWZ(d)) << 4)]);
                accO[n0d] = __builtin_amdgcn_mfma_f32_16x16x32_bf16(pf, vf, accO[n0d], 0, 0, 0);
            }
        }
        __syncthreads();   // before next tile overwrites sK/sV
    }

    // epilogue: O[q][d] / l[q]  (O layout: row q'=g*4+r, col d=n0d*16+li)
    const float invl = 1.f / lsum;
    float inv4[4];
    #pragma unroll
    for (int r = 0; r < 4; ++r) inv4[r] = __shfl(invl, (l & 48) | (g * 4 + r));
    #pragma unroll
    for (int n0d = 0; n0d < 4; ++n0d)
        #pragma unroll
        for (int r = 0; r < 4; ++r) {
            const int row = tok0 + w * 16 + g * 4 + r;
            const int d = n0d * 16 + li;
            X[(size_t)row * DD + col0 + d] = f2b(accO[n0d][r] * inv4[r]);
        }
}

// ---------------------------------------------------------------------------
extern "C" void kernel_launch(void* const* d_in, const int* in_sizes, int n_in,
                              void* d_out, int out_size, void* d_ws, size_t ws_size,
                              hipStream_t stream) {
    const float* query = (const float*)d_in[0];
    const float* key   = (const float*)d_in[1];
    const float* value = (const float*)d_in[2];
    // d_in[3] = mask (guaranteed tril; causal handled structurally)
    const float* Wq = (const float*)d_in[4];
    const float* bq = (const float*)d_in[5];
    const float* Wk = (const float*)d_in[6];
    const float* bk = (const float*)d_in[7];
    const float* Wv = (const float*)d_in[8];
    const float* bv = (const float*)d_in[9];
    const float* Wo = (const float*)d_in[10];
    const float* bo = (const float*)d_in[11];
    float* out = (float*)d_out;

    unsigned short* ws16 = (unsigned short*)d_ws;
    const size_t TOK = (size_t)NT * DD;          // 4M elems
    const size_t WSZ = (size_t)DD * DD;          // 1M elems
    unsigned short* xq  = ws16;
    unsigned short* xk  = ws16 + TOK;
    unsigned short* xv  = ws16 + 2 * TOK;
    unsigned short* qb  = ws16 + 3 * TOK;
    unsigned short* kb  = ws16 + 4 * TOK;
    unsigned short* vb  = ws16 + 5 * TOK;
    unsigned short* xb  = ws16 + 6 * TOK;
    unsigned short* wqb = ws16 + 7 * TOK;
    unsigned short* wkb = wqb + WSZ;
    unsigned short* wvb = wkb + WSZ;
    unsigned short* wob = wvb + WSZ;

    const int n4t = (int)(TOK / 4);
    const int n4w = (int)(WSZ / 4);
    cast_f32_bf16<<<2048, 256, 0, stream>>>(query, xq, n4t);
    cast_f32_bf16<<<2048, 256, 0, stream>>>(key,   xk, n4t);
    cast_f32_bf16<<<2048, 256, 0, stream>>>(value, xv, n4t);
    cast_f32_bf16<<<1024, 256, 0, stream>>>(Wq, wqb, n4w);
    cast_f32_bf16<<<1024, 256, 0, stream>>>(Wk, wkb, n4w);
    cast_f32_bf16<<<1024, 256, 0, stream>>>(Wv, wvb, n4w);
    cast_f32_bf16<<<1024, 256, 0, stream>>>(Wo, wob, n4w);

    const dim3 ggrid(DD / 128, NT / 128);   // (8, 32)
    gemm_bf16_mfma<unsigned short><<<ggrid, 256, 0, stream>>>(xq, wqb, bq, qb, NT, DD, DD);
    gemm_bf16_mfma<unsigned short><<<ggrid, 256, 0, stream>>>(xk, wkb, bk, kb, NT, DD, DD);
    gemm_bf16_mfma<unsigned short><<<ggrid, 256, 0, stream>>>(xv, wvb, bv, vb, NT, DD, DD);

    attn_mfma<<<dim3(SS / 64, HH, BB), 256, 0, stream>>>(qb, kb, vb, xb);

    gemm_bf16_mfma<float><<<ggrid, 256, 0, stream>>>(xb, wob, bo, out, NT, DD, DD);
}

// Round 3
// 316.725 us; speedup vs baseline: 8.2804x; 1.1662x over previous
//
#include <hip/hip_runtime.h>
#include <hip/hip_bf16.h>
#include <math.h>

#define BB 2
#define SS 2048
#define DD 1024
#define HH 16
#define DKK 64
#define NT (BB * SS)      // 4096 tokens
#define QBLK 128
#define NQT (SS / QBLK)   // 16

typedef __attribute__((ext_vector_type(8))) short short8;   // 8 bf16 = 4 VGPRs
typedef __attribute__((ext_vector_type(4))) float f32x4;

// XOR swizzle for 128B rows (8 x 16B chunks)
#define SWZ(r) ((((r) >> 3) ^ (r)) & 7)

__device__ __forceinline__ unsigned short f2b(float x) {
    __hip_bfloat16 h = __float2bfloat16(x);   // RNE; compiler pairs into v_cvt_pk_bf16_f32
    unsigned short u; __builtin_memcpy(&u, &h, 2); return u;
}

__device__ __forceinline__ f32x4 zero4() {
    f32x4 z; z[0] = 0.f; z[1] = 0.f; z[2] = 0.f; z[3] = 0.f; return z;
}

// ---------------------------------------------------------------------------
// Shared GEMM body: C[M][N] = A[M][K] @ W[N][K]^T + bias
// 128x128 tile, BK=64, 4 waves. W is fp32 (converted during staging).
// A is fp32 (converted) or bf16 per template.
// ---------------------------------------------------------------------------
template <typename AT, typename OutT>
__device__ __forceinline__ void gemm_body(const AT* __restrict__ A,
                                          const float* __restrict__ W,
                                          const float* __restrict__ bias,
                                          OutT* __restrict__ C,
                                          int bm, int bn, int N, int K) {
    __shared__ __align__(16) unsigned char sA[128 * 128];  // 128 rows x 64 bf16
    __shared__ __align__(16) unsigned char sB[128 * 128];

    const int tid = threadIdx.x;
    const int l = tid & 63;
    const int w = tid >> 6;
    const int wr = w >> 1, wc = w & 1;
    const int g = l >> 4, li = l & 15;

    f32x4 acc[4][4];
    #pragma unroll
    for (int i = 0; i < 4; ++i)
        #pragma unroll
        for (int jj = 0; jj < 4; ++jj) acc[i][jj] = zero4();

    for (int kt = 0; kt < K; kt += 64) {
        #pragma unroll
        for (int c = 0; c < 4; ++c) {
            const int ch = c * 256 + tid;
            const int row = ch >> 3, cj = ch & 7;
            short8 va, vb;
            if constexpr (sizeof(AT) == 4) {
                const float* p = (const float*)A + (size_t)(bm + row) * K + kt + cj * 8;
                const float4 a0 = *reinterpret_cast<const float4*>(p);
                const float4 a1 = *reinterpret_cast<const float4*>(p + 4);
                #pragma unroll
                for (int jj = 0; jj < 4; ++jj) {
                    va[jj]     = (short)f2b(((const float*)&a0)[jj]);
                    va[4 + jj] = (short)f2b(((const float*)&a1)[jj]);
                }
            } else {
                va = *reinterpret_cast<const short8*>(
                    (const unsigned short*)A + (size_t)(bm + row) * K + kt + cj * 8);
            }
            {
                const float* p = W + (size_t)(bn + row) * K + kt + cj * 8;
                const float4 b0 = *reinterpret_cast<const float4*>(p);
                const float4 b1 = *reinterpret_cast<const float4*>(p + 4);
                #pragma unroll
                for (int jj = 0; jj < 4; ++jj) {
                    vb[jj]     = (short)f2b(((const float*)&b0)[jj]);
                    vb[4 + jj] = (short)f2b(((const float*)&b1)[jj]);
                }
            }
            *reinterpret_cast<short8*>(&sA[row * 128 + ((cj ^ SWZ(row)) << 4)]) = va;
            *reinterpret_cast<short8*>(&sB[row * 128 + ((cj ^ SWZ(row)) << 4)]) = vb;
        }
        __syncthreads();

        #pragma unroll
        for (int kb = 0; kb < 2; ++kb) {
            short8 af[4], bfr[4];
            const int ch = g + kb * 4;
            #pragma unroll
            for (int mi = 0; mi < 4; ++mi) {
                const int row = wr * 64 + mi * 16 + li;
                af[mi] = *reinterpret_cast<const short8*>(&sA[row * 128 + ((ch ^ SWZ(row)) << 4)]);
            }
            #pragma unroll
            for (int ni = 0; ni < 4; ++ni) {
                const int row = wc * 64 + ni * 16 + li;
                bfr[ni] = *reinterpret_cast<const short8*>(&sB[row * 128 + ((ch ^ SWZ(row)) << 4)]);
            }
            #pragma unroll
            for (int mi = 0; mi < 4; ++mi)
                #pragma unroll
                for (int ni = 0; ni < 4; ++ni)
                    acc[mi][ni] = __builtin_amdgcn_mfma_f32_16x16x32_bf16(af[mi], bfr[ni], acc[mi][ni], 0, 0, 0);
        }
        __syncthreads();
    }

    // epilogue (C/D layout: col=l&15, row=(l>>4)*4+reg)
    #pragma unroll
    for (int ni = 0; ni < 4; ++ni) {
        const int col = bn + wc * 64 + ni * 16 + li;
        const float bv = bias[col];
        #pragma unroll
        for (int mi = 0; mi < 4; ++mi) {
            const int row0 = bm + wr * 64 + mi * 16 + g * 4;
            #pragma unroll
            for (int r = 0; r < 4; ++r) {
                const float v = acc[mi][ni][r] + bv;
                if constexpr (sizeof(OutT) == 2)
                    C[(size_t)(row0 + r) * N + col] = (OutT)f2b(v);
                else
                    C[(size_t)(row0 + r) * N + col] = (OutT)v;
            }
        }
    }
}

struct QKVArgs {
    const float* A[3];
    const float* W[3];
    const float* bias[3];
    unsigned short* C[3];
};

// QKV projections batched: 768 blocks = 3 GEMMs x 256 tiles, XCD-chunked.
__global__ __launch_bounds__(256)
void gemm_qkv(QKVArgs args) {
    const int bid = blockIdx.x;                      // 0..767
    const int i = (bid & 7) * 96 + (bid >> 3);       // bijective (768 % 8 == 0)
    const int z = i >> 8;
    const int rem = i & 255;
    const int by = rem >> 3, bx = rem & 7;
    gemm_body<float, unsigned short>(args.A[z], args.W[z], args.bias[z], args.C[z],
                                     by * 128, bx * 128, DD, DD);
}

// Output projection: bf16 A, fp32 W, fp32 out.
__global__ __launch_bounds__(256)
void gemm_out(const unsigned short* __restrict__ A, const float* __restrict__ W,
              const float* __restrict__ bias, float* __restrict__ C) {
    const int bid = blockIdx.x;                      // 0..255
    const int i = (bid & 7) * 32 + (bid >> 3);
    const int by = i >> 3, bx = i & 7;
    gemm_body<unsigned short, float>(A, W, bias, C, by * 128, bx * 128, DD, DD);
}

// ---------------------------------------------------------------------------
// bf16 MFMA causal flash attention. QBLK=128, 8 waves x 16 q-rows, KVBLK=64.
// Grid = 512 blocks, all co-resident (2/CU). (b,h) pinned to an XCD so its
// K/V (512 KB) stays in that XCD's L2; qt reversed so long blocks start first.
// ---------------------------------------------------------------------------
__global__ __launch_bounds__(512)
void attn_mfma(const unsigned short* __restrict__ Q,
               const unsigned short* __restrict__ Kb,
               const unsigned short* __restrict__ Vb,
               unsigned short* __restrict__ X) {
    __shared__ __align__(16) unsigned char sK[64 * 128];      // [kv][d] swizzled
    __shared__ __align__(16) unsigned char sV[64 * 128];      // [d][kv] swizzled (transposed)
    __shared__ __align__(16) unsigned char sP[8][16 * 128];   // per-wave [q][kv] swizzled

    const int bid = blockIdx.x;                 // 0..511
    const int j = bid >> 3;
    const int pair = (bid & 7) * 4 + (j >> 4);  // (b,h) -> fixed XCD
    const int qt = (NQT - 1) - (j & 15);        // longest first
    const int b = pair >> 4, h = pair & 15;

    const int tid = threadIdx.x, l = tid & 63, w = tid >> 6;
    const int g = l >> 4, li = l & 15;
    const int tok0 = b * SS + qt * QBLK;
    const int col0 = h * DKK;
    const float scale = 0.125f;

    short8 qf[2];
    {
        const size_t qrow = (size_t)(tok0 + w * 16 + li) * DD + col0;
        qf[0] = *reinterpret_cast<const short8*>(&Q[qrow + g * 8]);
        qf[1] = *reinterpret_cast<const short8*>(&Q[qrow + 32 + g * 8]);
    }

    f32x4 accO[4];
    #pragma unroll
    for (int i = 0; i < 4; ++i) accO[i] = zero4();
    float m = -INFINITY, lsum = 0.f;
    const int qglob = qt * QBLK + w * 16 + li;
    const int qminw = qt * QBLK + w * 16;
    const int ktmax = 2 * qt + 1;

    for (int kt = 0; kt <= ktmax; ++kt) {
        const int ktok0 = b * SS + kt * 64;

        // stage K (row-major swizzled) + V (transposed swizzled); 512 thr, 1 chunk each
        {
            const int row = tid >> 3, cj = tid & 7;
            const size_t gsrc = (size_t)(ktok0 + row) * DD + col0 + cj * 8;
            const short8 kv8 = *reinterpret_cast<const short8*>(&Kb[gsrc]);
            *reinterpret_cast<short8*>(&sK[row * 128 + ((cj ^ SWZ(row)) << 4)]) = kv8;
            const short8 vv8 = *reinterpret_cast<const short8*>(&Vb[gsrc]);
            #pragma unroll
            for (int jj = 0; jj < 8; ++jj) {
                const int d = cj * 8 + jj;
                *reinterpret_cast<unsigned short*>(
                    &sV[d * 128 + (((row >> 3) ^ SWZ(d)) << 4) + (row & 7) * 2]) =
                    (unsigned short)vv8[jj];
            }
        }
        __syncthreads();

        if (kt * 64 <= qminw + 15) {   // tile not fully masked for this wave
            // S = K . Q^T (swapped)
            f32x4 accS[4];
            #pragma unroll
            for (int n0 = 0; n0 < 4; ++n0) accS[n0] = zero4();
            #pragma unroll
            for (int n0 = 0; n0 < 4; ++n0) {
                #pragma unroll
                for (int kb = 0; kb < 2; ++kb) {
                    const int row = n0 * 16 + li;
                    const int ch = g + kb * 4;
                    const short8 kf = *reinterpret_cast<const short8*>(
                        &sK[row * 128 + ((ch ^ SWZ(row)) << 4)]);
                    accS[n0] = __builtin_amdgcn_mfma_f32_16x16x32_bf16(kf, qf[kb], accS[n0], 0, 0, 0);
                }
            }

            const bool needMask = (kt * 64 + 63) > qminw;
            float s[16];
            float tmax = -INFINITY;
            #pragma unroll
            for (int n0 = 0; n0 < 4; ++n0)
                #pragma unroll
                for (int r = 0; r < 4; ++r) {
                    float v = accS[n0][r] * scale;
                    if (needMask) {
                        const int kv = kt * 64 + n0 * 16 + g * 4 + r;
                        if (kv > qglob) v = -1e30f;
                    }
                    s[n0 * 4 + r] = v;
                    tmax = fmaxf(tmax, v);
                }
            tmax = fmaxf(tmax, __shfl_xor(tmax, 16));
            tmax = fmaxf(tmax, __shfl_xor(tmax, 32));
            const float mnew = fmaxf(m, tmax);
            const float corr = __expf(m - mnew);
            float psum = 0.f;
            #pragma unroll
            for (int i = 0; i < 16; ++i) { s[i] = __expf(s[i] - mnew); psum += s[i]; }
            psum += __shfl_xor(psum, 16);
            psum += __shfl_xor(psum, 32);
            lsum = lsum * corr + psum;
            m = mnew;

            // P -> per-wave LDS (row q=li, col kv); no barrier needed (same wave)
            #pragma unroll
            for (int n0 = 0; n0 < 4; ++n0)
                #pragma unroll
                for (int r = 0; r < 4; ++r) {
                    const int kv = n0 * 16 + g * 4 + r;
                    *reinterpret_cast<unsigned short*>(
                        &sP[w][li * 128 + (((kv >> 3) ^ SWZ(li)) << 4) + (kv & 7) * 2]) =
                        f2b(s[n0 * 4 + r]);
                }

            // rescale O by corr of q' = g*4+r
            float corr4[4];
            #pragma unroll
            for (int r = 0; r < 4; ++r) corr4[r] = __shfl(corr, (l & 48) | (g * 4 + r));
            #pragma unroll
            for (int n0d = 0; n0d < 4; ++n0d)
                #pragma unroll
                for (int r = 0; r < 4; ++r) accO[n0d][r] *= corr4[r];

            // O += P . V
            #pragma unroll
            for (int kb = 0; kb < 2; ++kb) {
                const int ch = g + kb * 4;
                const short8 pf = *reinterpret_cast<const short8*>(
                    &sP[w][li * 128 + ((ch ^ SWZ(li)) << 4)]);
                #pragma unroll
                for (int n0d = 0; n0d < 4; ++n0d) {
                    const int d = n0d * 16 + li;
                    const short8 vf = *reinterpret_cast<const short8*>(
                        &sV[d * 128 + ((ch ^ SWZ(d)) << 4)]);
                    accO[n0d] = __builtin_amdgcn_mfma_f32_16x16x32_bf16(pf, vf, accO[n0d], 0, 0, 0);
                }
            }
        }
        __syncthreads();
    }

    const float invl = 1.f / lsum;
    float inv4[4];
    #pragma unroll
    for (int r = 0; r < 4; ++r) inv4[r] = __shfl(invl, (l & 48) | (g * 4 + r));
    #pragma unroll
    for (int n0d = 0; n0d < 4; ++n0d)
        #pragma unroll
        for (int r = 0; r < 4; ++r) {
            const int row = tok0 + w * 16 + g * 4 + r;
            const int d = n0d * 16 + li;
            X[(size_t)row * DD + col0 + d] = f2b(accO[n0d][r] * inv4[r]);
        }
}

// ---------------------------------------------------------------------------
extern "C" void kernel_launch(void* const* d_in, const int* in_sizes, int n_in,
                              void* d_out, int out_size, void* d_ws, size_t ws_size,
                              hipStream_t stream) {
    const float* query = (const float*)d_in[0];
    const float* key   = (const float*)d_in[1];
    const float* value = (const float*)d_in[2];
    // d_in[3] = mask (guaranteed tril; causal handled structurally)
    const float* Wq = (const float*)d_in[4];
    const float* bq = (const float*)d_in[5];
    const float* Wk = (const float*)d_in[6];
    const float* bk = (const float*)d_in[7];
    const float* Wv = (const float*)d_in[8];
    const float* bv = (const float*)d_in[9];
    const float* Wo = (const float*)d_in[10];
    const float* bo = (const float*)d_in[11];
    float* out = (float*)d_out;

    unsigned short* ws16 = (unsigned short*)d_ws;
    const size_t TOK = (size_t)NT * DD;
    unsigned short* qb = ws16;
    unsigned short* kb = ws16 + TOK;
    unsigned short* vb = ws16 + 2 * TOK;
    unsigned short* xb = ws16 + 3 * TOK;

    QKVArgs args;
    args.A[0] = query; args.A[1] = key; args.A[2] = value;
    args.W[0] = Wq;    args.W[1] = Wk;  args.W[2] = Wv;
    args.bias[0] = bq; args.bias[1] = bk; args.bias[2] = bv;
    args.C[0] = qb;    args.C[1] = kb;  args.C[2] = vb;

    gemm_qkv<<<768, 256, 0, stream>>>(args);
    attn_mfma<<<512, 512, 0, stream>>>(qb, kb, vb, xb);
    gemm_out<<<256, 256, 0, stream>>>(xb, Wo, bo, out);
}

// Round 4
// 291.035 us; speedup vs baseline: 9.0113x; 1.0883x over previous
//
#include <hip/hip_runtime.h>
#include <hip/hip_bf16.h>
#include <math.h>

#define BB 2
#define SS 2048
#define DD 1024
#define HH 16
#define DKK 64
#define NT (BB * SS)      // 4096 tokens
#define QBLK 128
#define NQT (SS / QBLK)   // 16

typedef __attribute__((ext_vector_type(8))) short short8;   // 8 bf16 = 4 VGPRs
typedef __attribute__((ext_vector_type(4))) float f32x4;

// XOR swizzle for 128B rows (8 x 16B chunks) — used by attn only
#define SWZ(r) ((((r) >> 3) ^ (r)) & 7)

__device__ __forceinline__ unsigned short f2b(float x) {
    __hip_bfloat16 h = __float2bfloat16(x);   // RNE
    unsigned short u; __builtin_memcpy(&u, &h, 2); return u;
}

__device__ __forceinline__ f32x4 zero4() {
    f32x4 z; z[0] = 0.f; z[1] = 0.f; z[2] = 0.f; z[3] = 0.f; return z;
}

// ---------------------------------------------------------------------------
// Batched fp32 -> bf16 cast: 3 inputs (4.19M elem each) + 4 weights (1.05M).
// One launch; segment loop unrolled so pointers stay compile-time-indexed.
// ---------------------------------------------------------------------------
struct CastAll {
    const float* src[7];
    unsigned short* dst[7];
};

__global__ __launch_bounds__(256)
void cast_all(CastAll a) {
    const int tid0 = blockIdx.x * 256 + threadIdx.x;
    const int stride = gridDim.x * 256;
    #pragma unroll
    for (int s = 0; s < 7; ++s) {
        const int n4 = (s < 3) ? (NT * DD / 4) : (DD * DD / 4);
        const float* __restrict__ src = a.src[s];
        unsigned short* __restrict__ dst = a.dst[s];
        for (int i = tid0; i < n4; i += stride) {
            const float4 v = reinterpret_cast<const float4*>(src)[i];
            ushort4 o;
            o.x = f2b(v.x); o.y = f2b(v.y); o.z = f2b(v.z); o.w = f2b(v.w);
            reinterpret_cast<ushort4*>(dst)[i] = o;
        }
    }
}

// ---------------------------------------------------------------------------
// m97-structure bf16 MFMA GEMM: C[M][N] = A[M][K] @ W[N][K]^T + bias
// 128x128 tile, BK=64, 4 waves, global_load_lds width-16 staging into
// LINEAR LDS (dest = wave-uniform base + lane*16), ds_read_b128 fragments.
// ---------------------------------------------------------------------------
template <typename OutT>
__device__ __forceinline__ void gemm_body(const unsigned short* __restrict__ A,
                                          const unsigned short* __restrict__ W,
                                          const float* __restrict__ bias,
                                          OutT* __restrict__ C,
                                          int bm, int bn, int N, int K) {
    __shared__ __align__(16) unsigned char sA[128 * 128];  // [row][64 bf16] linear
    __shared__ __align__(16) unsigned char sB[128 * 128];

    const int tid = threadIdx.x;
    const int l = tid & 63;
    const int w = tid >> 6;            // wave id (uniform within wave)
    const int wr = w >> 1, wc = w & 1;
    const int g = l >> 4, li = l & 15;
    const int lrow = l >> 3;           // 0..7   (row within 8-row chunk)
    const int lcol = (l & 7) * 8;      // 0..56  (bf16 col offset)

    f32x4 acc[4][4];
    #pragma unroll
    for (int i = 0; i < 4; ++i)
        #pragma unroll
        for (int jj = 0; jj < 4; ++jj) acc[i][jj] = zero4();

    for (int kt = 0; kt < K; kt += 64) {
        // stage: each wave copies 32 rows of A and 32 rows of B (4 chunks each)
        #pragma unroll
        for (int c = 0; c < 4; ++c) {
            const int row0 = w * 32 + c * 8;                 // wave-uniform
            const unsigned short* gA = A + (size_t)(bm + row0 + lrow) * K + kt + lcol;
            __builtin_amdgcn_global_load_lds(
                (const __attribute__((address_space(1))) unsigned int*)gA,
                (__attribute__((address_space(3))) unsigned int*)&sA[row0 * 128],
                16, 0, 0);
            const unsigned short* gB = W + (size_t)(bn + row0 + lrow) * K + kt + lcol;
            __builtin_amdgcn_global_load_lds(
                (const __attribute__((address_space(1))) unsigned int*)gB,
                (__attribute__((address_space(3))) unsigned int*)&sB[row0 * 128],
                16, 0, 0);
        }
        __syncthreads();   // drains vmcnt + lgkmcnt

        #pragma unroll
        for (int kb = 0; kb < 2; ++kb) {
            const int chb = (g + kb * 4) * 16;   // byte offset of this lane's 16B chunk
            short8 af[4], bfr[4];
            #pragma unroll
            for (int mi = 0; mi < 4; ++mi)
                af[mi] = *reinterpret_cast<const short8*>(
                    &sA[(wr * 64 + mi * 16 + li) * 128 + chb]);
            #pragma unroll
            for (int ni = 0; ni < 4; ++ni)
                bfr[ni] = *reinterpret_cast<const short8*>(
                    &sB[(wc * 64 + ni * 16 + li) * 128 + chb]);
            #pragma unroll
            for (int mi = 0; mi < 4; ++mi)
                #pragma unroll
                for (int ni = 0; ni < 4; ++ni)
                    acc[mi][ni] = __builtin_amdgcn_mfma_f32_16x16x32_bf16(af[mi], bfr[ni], acc[mi][ni], 0, 0, 0);
        }
        __syncthreads();
    }

    // epilogue (C/D layout: col=l&15, row=(l>>4)*4+reg)
    #pragma unroll
    for (int ni = 0; ni < 4; ++ni) {
        const int col = bn + wc * 64 + ni * 16 + li;
        const float bv = bias[col];
        #pragma unroll
        for (int mi = 0; mi < 4; ++mi) {
            const int row0 = bm + wr * 64 + mi * 16 + g * 4;
            #pragma unroll
            for (int r = 0; r < 4; ++r) {
                const float v = acc[mi][ni][r] + bv;
                if constexpr (sizeof(OutT) == 2)
                    C[(size_t)(row0 + r) * N + col] = (OutT)f2b(v);
                else
                    C[(size_t)(row0 + r) * N + col] = (OutT)v;
            }
        }
    }
}

struct QKVArgs {
    const unsigned short* A[3];
    const unsigned short* W[3];
    const float* bias[3];
    unsigned short* C[3];
};

// QKV projections batched: 768 blocks = 3 GEMMs x 256 tiles, XCD-chunked.
__global__ __launch_bounds__(256)
void gemm_qkv(QKVArgs args) {
    const int bid = blockIdx.x;                      // 0..767
    const int i = (bid & 7) * 96 + (bid >> 3);       // bijective (768 % 8 == 0)
    const int z = i >> 8;
    const int rem = i & 255;
    const int by = rem >> 3, bx = rem & 7;
    gemm_body<unsigned short>(args.A[z], args.W[z], args.bias[z], args.C[z],
                              by * 128, bx * 128, DD, DD);
}

// Output projection: bf16 A and W, fp32 out.
__global__ __launch_bounds__(256)
void gemm_out(const unsigned short* __restrict__ A, const unsigned short* __restrict__ W,
              const float* __restrict__ bias, float* __restrict__ C) {
    const int bid = blockIdx.x;                      // 0..255
    const int i = (bid & 7) * 32 + (bid >> 3);
    const int by = i >> 3, bx = i & 7;
    gemm_body<float>(A, W, bias, C, by * 128, bx * 128, DD, DD);
}

// ---------------------------------------------------------------------------
// bf16 MFMA causal flash attention. QBLK=128, 8 waves x 16 q-rows, KVBLK=64.
// (unchanged from round 3)
// ---------------------------------------------------------------------------
__global__ __launch_bounds__(512)
void attn_mfma(const unsigned short* __restrict__ Q,
               const unsigned short* __restrict__ Kb,
               const unsigned short* __restrict__ Vb,
               unsigned short* __restrict__ X) {
    __shared__ __align__(16) unsigned char sK[64 * 128];      // [kv][d] swizzled
    __shared__ __align__(16) unsigned char sV[64 * 128];      // [d][kv] swizzled (transposed)
    __shared__ __align__(16) unsigned char sP[8][16 * 128];   // per-wave [q][kv] swizzled

    const int bid = blockIdx.x;                 // 0..511
    const int j = bid >> 3;
    const int pair = (bid & 7) * 4 + (j >> 4);  // (b,h) -> fixed XCD
    const int qt = (NQT - 1) - (j & 15);        // longest first
    const int b = pair >> 4, h = pair & 15;

    const int tid = threadIdx.x, l = tid & 63, w = tid >> 6;
    const int g = l >> 4, li = l & 15;
    const int tok0 = b * SS + qt * QBLK;
    const int col0 = h * DKK;
    const float scale = 0.125f;

    short8 qf[2];
    {
        const size_t qrow = (size_t)(tok0 + w * 16 + li) * DD + col0;
        qf[0] = *reinterpret_cast<const short8*>(&Q[qrow + g * 8]);
        qf[1] = *reinterpret_cast<const short8*>(&Q[qrow + 32 + g * 8]);
    }

    f32x4 accO[4];
    #pragma unroll
    for (int i = 0; i < 4; ++i) accO[i] = zero4();
    float m = -INFINITY, lsum = 0.f;
    const int qglob = qt * QBLK + w * 16 + li;
    const int qminw = qt * QBLK + w * 16;
    const int ktmax = 2 * qt + 1;

    for (int kt = 0; kt <= ktmax; ++kt) {
        const int ktok0 = b * SS + kt * 64;

        // stage K (row-major swizzled) + V (transposed swizzled); 512 thr, 1 chunk each
        {
            const int row = tid >> 3, cj = tid & 7;
            const size_t gsrc = (size_t)(ktok0 + row) * DD + col0 + cj * 8;
            const short8 kv8 = *reinterpret_cast<const short8*>(&Kb[gsrc]);
            *reinterpret_cast<short8*>(&sK[row * 128 + ((cj ^ SWZ(row)) << 4)]) = kv8;
            const short8 vv8 = *reinterpret_cast<const short8*>(&Vb[gsrc]);
            #pragma unroll
            for (int jj = 0; jj < 8; ++jj) {
                const int d = cj * 8 + jj;
                *reinterpret_cast<unsigned short*>(
                    &sV[d * 128 + (((row >> 3) ^ SWZ(d)) << 4) + (row & 7) * 2]) =
                    (unsigned short)vv8[jj];
            }
        }
        __syncthreads();

        if (kt * 64 <= qminw + 15) {   // tile not fully masked for this wave
            // S = K . Q^T (swapped)
            f32x4 accS[4];
            #pragma unroll
            for (int n0 = 0; n0 < 4; ++n0) accS[n0] = zero4();
            #pragma unroll
            for (int n0 = 0; n0 < 4; ++n0) {
                #pragma unroll
                for (int kb = 0; kb < 2; ++kb) {
                    const int row = n0 * 16 + li;
                    const int ch = g + kb * 4;
                    const short8 kf = *reinterpret_cast<const short8*>(
                        &sK[row * 128 + ((ch ^ SWZ(row)) << 4)]);
                    accS[n0] = __builtin_amdgcn_mfma_f32_16x16x32_bf16(kf, qf[kb], accS[n0], 0, 0, 0);
                }
            }

            const bool needMask = (kt * 64 + 63) > qminw;
            float s[16];
            float tmax = -INFINITY;
            #pragma unroll
            for (int n0 = 0; n0 < 4; ++n0)
                #pragma unroll
                for (int r = 0; r < 4; ++r) {
                    float v = accS[n0][r] * scale;
                    if (needMask) {
                        const int kv = kt * 64 + n0 * 16 + g * 4 + r;
                        if (kv > qglob) v = -1e30f;
                    }
                    s[n0 * 4 + r] = v;
                    tmax = fmaxf(tmax, v);
                }
            tmax = fmaxf(tmax, __shfl_xor(tmax, 16));
            tmax = fmaxf(tmax, __shfl_xor(tmax, 32));
            const float mnew = fmaxf(m, tmax);
            const float corr = __expf(m - mnew);
            float psum = 0.f;
            #pragma unroll
            for (int i = 0; i < 16; ++i) { s[i] = __expf(s[i] - mnew); psum += s[i]; }
            psum += __shfl_xor(psum, 16);
            psum += __shfl_xor(psum, 32);
            lsum = lsum * corr + psum;
            m = mnew;

            // P -> per-wave LDS (row q=li, col kv); same-wave ordering, no barrier
            #pragma unroll
            for (int n0 = 0; n0 < 4; ++n0)
                #pragma unroll
                for (int r = 0; r < 4; ++r) {
                    const int kv = n0 * 16 + g * 4 + r;
                    *reinterpret_cast<unsigned short*>(
                        &sP[w][li * 128 + (((kv >> 3) ^ SWZ(li)) << 4) + (kv & 7) * 2]) =
                        f2b(s[n0 * 4 + r]);
                }

            // rescale O by corr of q' = g*4+r
            float corr4[4];
            #pragma unroll
            for (int r = 0; r < 4; ++r) corr4[r] = __shfl(corr, (l & 48) | (g * 4 + r));
            #pragma unroll
            for (int n0d = 0; n0d < 4; ++n0d)
                #pragma unroll
                for (int r = 0; r < 4; ++r) accO[n0d][r] *= corr4[r];

            // O += P . V
            #pragma unroll
            for (int kb = 0; kb < 2; ++kb) {
                const int ch = g + kb * 4;
                const short8 pf = *reinterpret_cast<const short8*>(
                    &sP[w][li * 128 + ((ch ^ SWZ(li)) << 4)]);
                #pragma unroll
                for (int n0d = 0; n0d < 4; ++n0d) {
                    const int d = n0d * 16 + li;
                    const short8 vf = *reinterpret_cast<const short8*>(
                        &sV[d * 128 + ((ch ^ SWZ(d)) << 4)]);
                    accO[n0d] = __builtin_amdgcn_mfma_f32_16x16x32_bf16(pf, vf, accO[n0d], 0, 0, 0);
                }
            }
        }
        __syncthreads();
    }

    const float invl = 1.f / lsum;
    float inv4[4];
    #pragma unroll
    for (int r = 0; r < 4; ++r) inv4[r] = __shfl(invl, (l & 48) | (g * 4 + r));
    #pragma unroll
    for (int n0d = 0; n0d < 4; ++n0d)
        #pragma unroll
        for (int r = 0; r < 4; ++r) {
            const int row = tok0 + w * 16 + g * 4 + r;
            const int d = n0d * 16 + li;
            X[(size_t)row * DD + col0 + d] = f2b(accO[n0d][r] * inv4[r]);
        }
}

// ---------------------------------------------------------------------------
extern "C" void kernel_launch(void* const* d_in, const int* in_sizes, int n_in,
                              void* d_out, int out_size, void* d_ws, size_t ws_size,
                              hipStream_t stream) {
    const float* query = (const float*)d_in[0];
    const float* key   = (const float*)d_in[1];
    const float* value = (const float*)d_in[2];
    // d_in[3] = mask (guaranteed tril; causal handled structurally)
    const float* Wq = (const float*)d_in[4];
    const float* bq = (const float*)d_in[5];
    const float* Wk = (const float*)d_in[6];
    const float* bk = (const float*)d_in[7];
    const float* Wv = (const float*)d_in[8];
    const float* bv = (const float*)d_in[9];
    const float* Wo = (const float*)d_in[10];
    const float* bo = (const float*)d_in[11];
    float* out = (float*)d_out;

    unsigned short* ws16 = (unsigned short*)d_ws;
    const size_t TOK = (size_t)NT * DD;   // 4.19M elems
    const size_t WSZ = (size_t)DD * DD;   // 1.05M elems
    unsigned short* qb  = ws16;
    unsigned short* kb  = ws16 + TOK;
    unsigned short* vb  = ws16 + 2 * TOK;
    unsigned short* xb  = ws16 + 3 * TOK;
    unsigned short* xqb = ws16 + 4 * TOK;
    unsigned short* xkb = ws16 + 5 * TOK;
    unsigned short* xvb = ws16 + 6 * TOK;
    unsigned short* wqb = ws16 + 7 * TOK;
    unsigned short* wkb = wqb + WSZ;
    unsigned short* wvb = wkb + WSZ;
    unsigned short* wob = wvb + WSZ;

    CastAll ca;
    ca.src[0] = query; ca.dst[0] = xqb;
    ca.src[1] = key;   ca.dst[1] = xkb;
    ca.src[2] = value; ca.dst[2] = xvb;
    ca.src[3] = Wq;    ca.dst[3] = wqb;
    ca.src[4] = Wk;    ca.dst[4] = wkb;
    ca.src[5] = Wv;    ca.dst[5] = wvb;
    ca.src[6] = Wo;    ca.dst[6] = wob;
    cast_all<<<2048, 256, 0, stream>>>(ca);

    QKVArgs args;
    args.A[0] = xqb; args.A[1] = xkb; args.A[2] = xvb;
    args.W[0] = wqb; args.W[1] = wkb; args.W[2] = wvb;
    args.bias[0] = bq; args.bias[1] = bk; args.bias[2] = bv;
    args.C[0] = qb;  args.C[1] = kb;  args.C[2] = vb;
    gemm_qkv<<<768, 256, 0, stream>>>(args);

    attn_mfma<<<512, 512, 0, stream>>>(qb, kb, vb, xb);

    gemm_out<<<256, 256, 0, stream>>>(xb, wob, bo, out);
}

// Round 5
// 267.519 us; speedup vs baseline: 9.8035x; 1.0879x over previous
//
#include <hip/hip_runtime.h>
#include <hip/hip_bf16.h>
#include <math.h>

#define BB 2
#define SS 2048
#define DD 1024
#define HH 16
#define DKK 64
#define NT (BB * SS)      // 4096 tokens

typedef __attribute__((ext_vector_type(8))) short short8;   // 8 bf16 = 4 VGPRs
typedef __attribute__((ext_vector_type(4))) short short4v;  // 4 bf16 = 2 VGPRs
typedef __attribute__((ext_vector_type(4))) float f32x4;

// XOR swizzle for 128B rows (8 x 16B chunks) — used by attn only
#define SWZ(r) ((((r) >> 3) ^ (r)) & 7)

__device__ __forceinline__ unsigned short f2b(float x) {
    __hip_bfloat16 h = __float2bfloat16(x);   // RNE
    unsigned short u; __builtin_memcpy(&u, &h, 2); return u;
}

__device__ __forceinline__ f32x4 zero4() {
    f32x4 z; z[0] = 0.f; z[1] = 0.f; z[2] = 0.f; z[3] = 0.f; return z;
}

// ---------------------------------------------------------------------------
// Batched fp32 -> bf16 cast: 3 inputs (4.19M elem each) + 4 weights (1.05M).
// ---------------------------------------------------------------------------
struct CastAll {
    const float* src[7];
    unsigned short* dst[7];
};

__global__ __launch_bounds__(256)
void cast_all(CastAll a) {
    const int tid0 = blockIdx.x * 256 + threadIdx.x;
    const int stride = gridDim.x * 256;
    #pragma unroll
    for (int s = 0; s < 7; ++s) {
        const int n4 = (s < 3) ? (NT * DD / 4) : (DD * DD / 4);
        const float* __restrict__ src = a.src[s];
        unsigned short* __restrict__ dst = a.dst[s];
        for (int i = tid0; i < n4; i += stride) {
            const float4 v = reinterpret_cast<const float4*>(src)[i];
            ushort4 o;
            o.x = f2b(v.x); o.y = f2b(v.y); o.z = f2b(v.z); o.w = f2b(v.w);
            reinterpret_cast<ushort4*>(dst)[i] = o;
        }
    }
}

// ---------------------------------------------------------------------------
// m97-structure bf16 MFMA GEMM: C[M][N] = A[M][K] @ W[N][K]^T + bias
// 128x128 tile, BK=64, 4 waves, global_load_lds width-16 staging into
// LINEAR LDS, ds_read_b128 fragments.  (unchanged from round 4)
// ---------------------------------------------------------------------------
template <typename OutT>
__device__ __forceinline__ void gemm_body(const unsigned short* __restrict__ A,
                                          const unsigned short* __restrict__ W,
                                          const float* __restrict__ bias,
                                          OutT* __restrict__ C,
                                          int bm, int bn, int N, int K) {
    __shared__ __align__(16) unsigned char sA[128 * 128];
    __shared__ __align__(16) unsigned char sB[128 * 128];

    const int tid = threadIdx.x;
    const int l = tid & 63;
    const int w = tid >> 6;
    const int wr = w >> 1, wc = w & 1;
    const int g = l >> 4, li = l & 15;
    const int lrow = l >> 3;
    const int lcol = (l & 7) * 8;

    f32x4 acc[4][4];
    #pragma unroll
    for (int i = 0; i < 4; ++i)
        #pragma unroll
        for (int jj = 0; jj < 4; ++jj) acc[i][jj] = zero4();

    for (int kt = 0; kt < K; kt += 64) {
        #pragma unroll
        for (int c = 0; c < 4; ++c) {
            const int row0 = w * 32 + c * 8;
            const unsigned short* gA = A + (size_t)(bm + row0 + lrow) * K + kt + lcol;
            __builtin_amdgcn_global_load_lds(
                (const __attribute__((address_space(1))) unsigned int*)gA,
                (__attribute__((address_space(3))) unsigned int*)&sA[row0 * 128],
                16, 0, 0);
            const unsigned short* gB = W + (size_t)(bn + row0 + lrow) * K + kt + lcol;
            __builtin_amdgcn_global_load_lds(
                (const __attribute__((address_space(1))) unsigned int*)gB,
                (__attribute__((address_space(3))) unsigned int*)&sB[row0 * 128],
                16, 0, 0);
        }
        __syncthreads();

        #pragma unroll
        for (int kb = 0; kb < 2; ++kb) {
            const int chb = (g + kb * 4) * 16;
            short8 af[4], bfr[4];
            #pragma unroll
            for (int mi = 0; mi < 4; ++mi)
                af[mi] = *reinterpret_cast<const short8*>(
                    &sA[(wr * 64 + mi * 16 + li) * 128 + chb]);
            #pragma unroll
            for (int ni = 0; ni < 4; ++ni)
                bfr[ni] = *reinterpret_cast<const short8*>(
                    &sB[(wc * 64 + ni * 16 + li) * 128 + chb]);
            #pragma unroll
            for (int mi = 0; mi < 4; ++mi)
                #pragma unroll
                for (int ni = 0; ni < 4; ++ni)
                    acc[mi][ni] = __builtin_amdgcn_mfma_f32_16x16x32_bf16(af[mi], bfr[ni], acc[mi][ni], 0, 0, 0);
        }
        __syncthreads();
    }

    #pragma unroll
    for (int ni = 0; ni < 4; ++ni) {
        const int col = bn + wc * 64 + ni * 16 + li;
        const float bv = bias[col];
        #pragma unroll
        for (int mi = 0; mi < 4; ++mi) {
            const int row0 = bm + wr * 64 + mi * 16 + g * 4;
            #pragma unroll
            for (int r = 0; r < 4; ++r) {
                const float v = acc[mi][ni][r] + bv;
                if constexpr (sizeof(OutT) == 2)
                    C[(size_t)(row0 + r) * N + col] = (OutT)f2b(v);
                else
                    C[(size_t)(row0 + r) * N + col] = (OutT)v;
            }
        }
    }
}

struct QKVArgs {
    const unsigned short* A[3];
    const unsigned short* W[3];
    const float* bias[3];
    unsigned short* C[3];
};

__global__ __launch_bounds__(256)
void gemm_qkv(QKVArgs args) {
    const int bid = blockIdx.x;                      // 0..767
    const int i = (bid & 7) * 96 + (bid >> 3);       // bijective (768 % 8 == 0)
    const int z = i >> 8;
    const int rem = i & 255;
    const int by = rem >> 3, bx = rem & 7;
    gemm_body<unsigned short>(args.A[z], args.W[z], args.bias[z], args.C[z],
                              by * 128, bx * 128, DD, DD);
}

__global__ __launch_bounds__(256)
void gemm_out(const unsigned short* __restrict__ A, const unsigned short* __restrict__ W,
              const float* __restrict__ bias, float* __restrict__ C) {
    const int bid = blockIdx.x;                      // 0..255
    const int i = (bid & 7) * 32 + (bid >> 3);
    const int by = i >> 3, bx = i & 7;
    gemm_body<float>(A, W, bias, C, by * 128, bx * 128, DD, DD);
}

// ---------------------------------------------------------------------------
// bf16 MFMA causal flash attention — LOAD-BALANCED pairing.
// Block = (b,h, pair p): waves 0-3 own 64-row q-tile jA=p, waves 4-7 own
// jB=31-p. kv loop kt=0..31-p stages each K/V tile once for both groups;
// per-wave skip idles the short group past its diagonal.
// Cost per block = (p+1) + (32-p) = 33 tile-units, uniform across all 512.
// ---------------------------------------------------------------------------
__global__ __launch_bounds__(512)
void attn_mfma(const unsigned short* __restrict__ Q,
               const unsigned short* __restrict__ Kb,
               const unsigned short* __restrict__ Vb,
               unsigned short* __restrict__ X) {
    __shared__ __align__(16) unsigned char sK[64 * 128];      // [kv][d] swizzled
    __shared__ __align__(16) unsigned char sV[64 * 128];      // [d][kv] swizzled (transposed)
    __shared__ __align__(16) unsigned char sP[8][16 * 128];   // per-wave [q][kv] swizzled

    const int bid = blockIdx.x;                 // 0..511
    const int t = bid >> 3;                     // 0..63
    const int bh = (bid & 7) + 8 * (t & 3);     // 0..31; bid%8 pins 4 bh per XCD
    const int p = t >> 2;                       // pair index 0..15
    const int b = bh >> 4, h = bh & 15;

    const int tid = threadIdx.x, l = tid & 63, w = tid >> 6;
    const int g = l >> 4, li = l & 15;
    const int jsel = (w < 4) ? p : (31 - p);    // this wave's 64-row q-tile
    const int rowb = jsel * 64 + (w & 3) * 16;  // seq-local first q-row of wave
    const int col0 = h * DKK;
    const float scale = 0.125f;

    short8 qf[2];
    {
        const size_t qrow = (size_t)(b * SS + rowb + li) * DD + col0;
        qf[0] = *reinterpret_cast<const short8*>(&Q[qrow + g * 8]);
        qf[1] = *reinterpret_cast<const short8*>(&Q[qrow + 32 + g * 8]);
    }

    f32x4 accO[4];
    #pragma unroll
    for (int i = 0; i < 4; ++i) accO[i] = zero4();
    float m = -INFINITY, lsum = 0.f;
    const int qglob = rowb + li;                // the q-row this lane tracks
    const int nkt = 31 - p;                     // last kv tile index

    for (int kt = 0; kt <= nkt; ++kt) {
        const int ktok0 = b * SS + kt * 64;

        // stage K (row-major swizzled) + V (transposed swizzled); 512 thr
        {
            const int row = tid >> 3, cj = tid & 7;
            const size_t gsrc = (size_t)(ktok0 + row) * DD + col0 + cj * 8;
            const short8 kv8 = *reinterpret_cast<const short8*>(&Kb[gsrc]);
            *reinterpret_cast<short8*>(&sK[row * 128 + ((cj ^ SWZ(row)) << 4)]) = kv8;
            const short8 vv8 = *reinterpret_cast<const short8*>(&Vb[gsrc]);
            #pragma unroll
            for (int jj = 0; jj < 8; ++jj) {
                const int d = cj * 8 + jj;
                *reinterpret_cast<unsigned short*>(
                    &sV[d * 128 + (((row >> 3) ^ SWZ(d)) << 4) + (row & 7) * 2]) =
                    (unsigned short)vv8[jj];
            }
        }
        __syncthreads();

        if (kt * 64 <= rowb + 15) {   // tile not fully masked for this wave
            // S = K . Q^T (swapped)
            f32x4 accS[4];
            #pragma unroll
            for (int n0 = 0; n0 < 4; ++n0) accS[n0] = zero4();
            __builtin_amdgcn_s_setprio(1);
            #pragma unroll
            for (int n0 = 0; n0 < 4; ++n0) {
                #pragma unroll
                for (int kb = 0; kb < 2; ++kb) {
                    const int row = n0 * 16 + li;
                    const int ch = g + kb * 4;
                    const short8 kf = *reinterpret_cast<const short8*>(
                        &sK[row * 128 + ((ch ^ SWZ(row)) << 4)]);
                    accS[n0] = __builtin_amdgcn_mfma_f32_16x16x32_bf16(kf, qf[kb], accS[n0], 0, 0, 0);
                }
            }
            __builtin_amdgcn_s_setprio(0);

            const bool needMask = (kt * 64 + 63) > rowb;
            float s[16];
            float tmax = -INFINITY;
            #pragma unroll
            for (int n0 = 0; n0 < 4; ++n0)
                #pragma unroll
                for (int r = 0; r < 4; ++r) {
                    float v = accS[n0][r] * scale;
                    if (needMask) {
                        const int kv = kt * 64 + n0 * 16 + g * 4 + r;
                        if (kv > qglob) v = -1e30f;
                    }
                    s[n0 * 4 + r] = v;
                    tmax = fmaxf(tmax, v);
                }
            tmax = fmaxf(tmax, __shfl_xor(tmax, 16));
            tmax = fmaxf(tmax, __shfl_xor(tmax, 32));
            const float mnew = fmaxf(m, tmax);
            const float corr = __expf(m - mnew);
            float psum = 0.f;
            #pragma unroll
            for (int i = 0; i < 16; ++i) { s[i] = __expf(s[i] - mnew); psum += s[i]; }
            psum += __shfl_xor(psum, 16);
            psum += __shfl_xor(psum, 32);
            lsum = lsum * corr + psum;
            m = mnew;

            // P -> per-wave LDS, packed 4x bf16 per ds_write_b64.
            // kv = n0*16 + g*4 + r, r=0..3 contiguous: granule (n0*2+(g>>1))^SWZ(li),
            // byte offset (g&1)*8 within granule.
            #pragma unroll
            for (int n0 = 0; n0 < 4; ++n0) {
                short4v pk;
                #pragma unroll
                for (int r = 0; r < 4; ++r) pk[r] = (short)f2b(s[n0 * 4 + r]);
                *reinterpret_cast<short4v*>(
                    &sP[w][li * 128 + (((n0 * 2 + (g >> 1)) ^ SWZ(li)) << 4) + (g & 1) * 8]) = pk;
            }

            // rescale O by corr of q' = g*4+r
            float corr4[4];
            #pragma unroll
            for (int r = 0; r < 4; ++r) corr4[r] = __shfl(corr, (l & 48) | (g * 4 + r));
            #pragma unroll
            for (int n0d = 0; n0d < 4; ++n0d)
                #pragma unroll
                for (int r = 0; r < 4; ++r) accO[n0d][r] *= corr4[r];

            // O += P . V
            __builtin_amdgcn_s_setprio(1);
            #pragma unroll
            for (int kb = 0; kb < 2; ++kb) {
                const int ch = g + kb * 4;
                const short8 pf = *reinterpret_cast<const short8*>(
                    &sP[w][li * 128 + ((ch ^ SWZ(li)) << 4)]);
                #pragma unroll
                for (int n0d = 0; n0d < 4; ++n0d) {
                    const int d = n0d * 16 + li;
                    const short8 vf = *reinterpret_cast<const short8*>(
                        &sV[d * 128 + ((ch ^ SWZ(d)) << 4)]);
                    accO[n0d] = __builtin_amdgcn_mfma_f32_16x16x32_bf16(pf, vf, accO[n0d], 0, 0, 0);
                }
            }
            __builtin_amdgcn_s_setprio(0);
        }
        __syncthreads();
    }

    const float invl = 1.f / lsum;
    float inv4[4];
    #pragma unroll
    for (int r = 0; r < 4; ++r) inv4[r] = __shfl(invl, (l & 48) | (g * 4 + r));
    #pragma unroll
    for (int n0d = 0; n0d < 4; ++n0d)
        #pragma unroll
        for (int r = 0; r < 4; ++r) {
            const int row = b * SS + rowb + g * 4 + r;
            const int d = n0d * 16 + li;
            X[(size_t)row * DD + col0 + d] = f2b(accO[n0d][r] * inv4[r]);
        }
}

// ---------------------------------------------------------------------------
extern "C" void kernel_launch(void* const* d_in, const int* in_sizes, int n_in,
                              void* d_out, int out_size, void* d_ws, size_t ws_size,
                              hipStream_t stream) {
    const float* query = (const float*)d_in[0];
    const float* key   = (const float*)d_in[1];
    const float* value = (const float*)d_in[2];
    // d_in[3] = mask (guaranteed tril; causal handled structurally)
    const float* Wq = (const float*)d_in[4];
    const float* bq = (const float*)d_in[5];
    const float* Wk = (const float*)d_in[6];
    const float* bk = (const float*)d_in[7];
    const float* Wv = (const float*)d_in[8];
    const float* bv = (const float*)d_in[9];
    const float* Wo = (const float*)d_in[10];
    const float* bo = (const float*)d_in[11];
    float* out = (float*)d_out;

    unsigned short* ws16 = (unsigned short*)d_ws;
    const size_t TOK = (size_t)NT * DD;   // 4.19M elems
    const size_t WSZ = (size_t)DD * DD;   // 1.05M elems
    unsigned short* qb  = ws16;
    unsigned short* kb  = ws16 + TOK;
    unsigned short* vb  = ws16 + 2 * TOK;
    unsigned short* xb  = ws16 + 3 * TOK;
    unsigned short* xqb = ws16 + 4 * TOK;
    unsigned short* xkb = ws16 + 5 * TOK;
    unsigned short* xvb = ws16 + 6 * TOK;
    unsigned short* wqb = ws16 + 7 * TOK;
    unsigned short* wkb = wqb + WSZ;
    unsigned short* wvb = wkb + WSZ;
    unsigned short* wob = wvb + WSZ;

    CastAll ca;
    ca.src[0] = query; ca.dst[0] = xqb;
    ca.src[1] = key;   ca.dst[1] = xkb;
    ca.src[2] = value; ca.dst[2] = xvb;
    ca.src[3] = Wq;    ca.dst[3] = wqb;
    ca.src[4] = Wk;    ca.dst[4] = wkb;
    ca.src[5] = Wv;    ca.dst[5] = wvb;
    ca.src[6] = Wo;    ca.dst[6] = wob;
    cast_all<<<2048, 256, 0, stream>>>(ca);

    QKVArgs args;
    args.A[0] = xqb; args.A[1] = xkb; args.A[2] = xvb;
    args.W[0] = wqb; args.W[1] = wkb; args.W[2] = wvb;
    args.bias[0] = bq; args.bias[1] = bk; args.bias[2] = bv;
    args.C[0] = qb;  args.C[1] = kb;  args.C[2] = vb;
    gemm_qkv<<<768, 256, 0, stream>>>(args);

    attn_mfma<<<512, 512, 0, stream>>>(qb, kb, vb, xb);

    gemm_out<<<256, 256, 0, stream>>>(xb, wob, bo, out);
}